// Round 15
// baseline (52.393 us; speedup 1.0000x reference)
//
#include <hip/hip_runtime.h>
#include <hip/hip_bf16.h>
#include <cstddef>

// Pipeline:
//  kPrep   : W split-bf16 transpose (+ encT transpose when ws has room)
//  kMgemmB : split-bf16 3-term MFMA GEMM, 32x128 tile; epilogue stores
//            exp2 of prescaled activation (factored sigmoid)
//  kLogits : factored-sigmoid scores, 2-t sharing + forced 8 waves/SIMD
//            (r14: 4-t at ~75 VGPR = 4 waves/SIMD; occupancy was the cap)
//  kEncT   : standalone fallback when encT must reuse X1e space
//  kSoftW  : softmax per (b,t), f32 weights in-place
//  kCtxMM  : MFMA batched context GEMM, f32->bf16 weights in A-staging

constexpr int nBt = 16, nSq = 128, nTq = 128, nEd = 512;

typedef __attribute__((ext_vector_type(4))) float f32x4;
typedef __attribute__((ext_vector_type(8))) short s16x8;

#define PRESCALE 2.8853900817779268f  /* 2*log2(e) */
#define LOG2E 1.4426950408889634f

__device__ __forceinline__ unsigned short to_bf(float f) {
    unsigned u = __builtin_bit_cast(unsigned, f);
    return (unsigned short)((u + 0x7FFFu + ((u >> 16) & 1u)) >> 16);  // RNE
}
__device__ __forceinline__ float from_bf(unsigned short h) {
    unsigned u = ((unsigned)h) << 16;
    return __builtin_bit_cast(float, u);
}

// ---- kPrep: [0,512) W-split blocks; [512,1536) encT blocks (if early) ---
__global__ __launch_bounds__(256) void kPrep(
    const float* __restrict__ W1, const float* __restrict__ W2,
    unsigned short* __restrict__ WT,
    const float* __restrict__ enc, unsigned short* __restrict__ encT)
{
    __shared__ float tl[32][33];
    const int r  = threadIdx.x >> 3;
    const int c4 = (threadIdx.x & 7) * 4;
    int bid = blockIdx.x;

    if (bid < 512) {   // W split-transpose (r8-proven math)
        const int z = bid >> 8;
        const int yx = bid & 255;
        const int kB = (yx >> 4) * 32;
        const int nB = (yx & 15) * 32;
        const float* W = z ? W2 : W1;
        const float4 v = *(const float4*)&W[(size_t)(kB + r) * nEd + nB + c4];
        tl[r][c4 + 0] = v.x; tl[r][c4 + 1] = v.y;
        tl[r][c4 + 2] = v.z; tl[r][c4 + 3] = v.w;
        __syncthreads();
        unsigned short hh[4], ll[4];
        #pragma unroll
        for (int i = 0; i < 4; ++i) {
            const float x = tl[c4 + i][r];
            hh[i] = to_bf(x);
            ll[i] = to_bf(x - from_bf(hh[i]));
        }
        const size_t o = ((size_t)z * nEd + nB + r) * nEd + kB + c4;
        *(ushort4*)&WT[o] = *(ushort4*)hh;
        *(ushort4*)&WT[(size_t)2 * nEd * nEd + o] = *(ushort4*)ll;
    } else {           // encT transpose (r9-proven math)
        bid -= 512;
        const int b = bid >> 6;
        const int r6 = bid & 63;
        const int eB = (r6 & 15) * 32;
        const int sB = (r6 >> 4) * 32;
        const float4 v = *(const float4*)&enc[((size_t)b * nSq + sB + r) * nEd + eB + c4];
        tl[r][c4 + 0] = v.x; tl[r][c4 + 1] = v.y;
        tl[r][c4 + 2] = v.z; tl[r][c4 + 3] = v.w;
        __syncthreads();
        unsigned short o[4];
        #pragma unroll
        for (int i = 0; i < 4; ++i) o[i] = to_bf(tl[c4 + i][r]);
        *(ushort4*)&encT[((size_t)b * nEd + eB + r) * nSq + sB + c4] = *(ushort4*)o;
    }
}

// ---- kEncT: standalone fallback (r9-proven) -----------------------------
__global__ __launch_bounds__(256) void kEncT(
    const float* __restrict__ enc, unsigned short* __restrict__ encT)
{
    const int b = blockIdx.z;
    __shared__ float tl[32][33];
    const int r  = threadIdx.x >> 3;
    const int c4 = (threadIdx.x & 7) * 4;
    const int sB = blockIdx.y * 32;
    const int eB = blockIdx.x * 32;
    const float4 v = *(const float4*)&enc[((size_t)b * nSq + sB + r) * nEd + eB + c4];
    tl[r][c4 + 0] = v.x; tl[r][c4 + 1] = v.y;
    tl[r][c4 + 2] = v.z; tl[r][c4 + 3] = v.w;
    __syncthreads();
    unsigned short o[4];
    #pragma unroll
    for (int i = 0; i < 4; ++i) o[i] = to_bf(tl[c4 + i][r]);
    *(ushort4*)&encT[((size_t)b * nEd + eB + r) * nSq + sB + c4] = *(ushort4*)o;
}

// ---- kMgemmB: C_z = exp2((A_z @ W_z [+bias]) * PRESCALE) (r11-14 proven)
__global__ __launch_bounds__(256) void kMgemmB(
    const float* __restrict__ A0, const float* __restrict__ A1,
    const unsigned short* __restrict__ WT, const float* __restrict__ bias,
    float* __restrict__ C0, float* __restrict__ C1)
{
    const int z = blockIdx.z;
    const float* __restrict__ A = z ? A1 : A0;
    const unsigned short* __restrict__ Wh = WT + (size_t)z * nEd * nEd;
    const unsigned short* __restrict__ Wl = Wh + (size_t)2 * nEd * nEd;
    float* __restrict__ C = z ? C1 : C0;

    __shared__ unsigned short sAh[32][72];
    __shared__ unsigned short sAl[32][72];
    __shared__ unsigned short sBh[128][72];
    __shared__ unsigned short sBl[128][72];

    const int tid  = threadIdx.x;
    const int lane = tid & 63;
    const int wv   = tid >> 6;
    const int rowB = blockIdx.y * 32;
    const int colB = blockIdx.x * 128;

    const int ar = tid >> 3, ak = (tid & 7) * 8;
    const int br = tid >> 1, bc = (tid & 1) * 32;

    f32x4 acc[2][2] = {};
    const int l15 = lane & 15;
    const int kh  = lane >> 4;

    for (int k0 = 0; k0 < nEd; k0 += 64) {
        const float4 ga0 = *(const float4*)&A[(size_t)(rowB + ar) * nEd + k0 + ak];
        const float4 ga1 = *(const float4*)&A[(size_t)(rowB + ar) * nEd + k0 + ak + 4];
        const size_t wo = (size_t)(colB + br) * nEd + k0 + bc;
        s16x8 gh[4], gl[4];
        #pragma unroll
        for (int j = 0; j < 4; ++j) {
            gh[j] = *(const s16x8*)&Wh[wo + 8 * j];
            gl[j] = *(const s16x8*)&Wl[wo + 8 * j];
        }

        __syncthreads();
        {
            const float a8[8] = {ga0.x, ga0.y, ga0.z, ga0.w,
                                 ga1.x, ga1.y, ga1.z, ga1.w};
            unsigned short h[8], l[8];
            #pragma unroll
            for (int i = 0; i < 8; ++i) {
                h[i] = to_bf(a8[i]);
                l[i] = to_bf(a8[i] - from_bf(h[i]));
            }
            *(ushort4*)&sAh[ar][ak]     = *(ushort4*)&h[0];
            *(ushort4*)&sAh[ar][ak + 4] = *(ushort4*)&h[4];
            *(ushort4*)&sAl[ar][ak]     = *(ushort4*)&l[0];
            *(ushort4*)&sAl[ar][ak + 4] = *(ushort4*)&l[4];
        }
        #pragma unroll
        for (int j = 0; j < 4; ++j) {
            *(s16x8*)&sBh[br][bc + 8 * j] = gh[j];
            *(s16x8*)&sBl[br][bc + 8 * j] = gl[j];
        }
        __syncthreads();

        #pragma unroll
        for (int kk = 0; kk < 2; ++kk) {
            s16x8 fAh[2], fAl[2], fBh[2], fBl[2];
            #pragma unroll
            for (int mi = 0; mi < 2; ++mi) {
                fAh[mi] = *(const s16x8*)&sAh[mi * 16 + l15][kk * 32 + kh * 8];
                fAl[mi] = *(const s16x8*)&sAl[mi * 16 + l15][kk * 32 + kh * 8];
            }
            #pragma unroll
            for (int ni = 0; ni < 2; ++ni) {
                fBh[ni] = *(const s16x8*)&sBh[wv * 32 + ni * 16 + l15][kk * 32 + kh * 8];
                fBl[ni] = *(const s16x8*)&sBl[wv * 32 + ni * 16 + l15][kk * 32 + kh * 8];
            }
            #pragma unroll
            for (int mi = 0; mi < 2; ++mi)
                #pragma unroll
                for (int ni = 0; ni < 2; ++ni) {
                    f32x4 a = acc[mi][ni];
                    a = __builtin_amdgcn_mfma_f32_16x16x32_bf16(fAh[mi], fBh[ni], a, 0, 0, 0);
                    a = __builtin_amdgcn_mfma_f32_16x16x32_bf16(fAl[mi], fBh[ni], a, 0, 0, 0);
                    a = __builtin_amdgcn_mfma_f32_16x16x32_bf16(fAh[mi], fBl[ni], a, 0, 0, 0);
                    acc[mi][ni] = a;
                }
        }
    }

    #pragma unroll
    for (int ni = 0; ni < 2; ++ni) {
        const int col = colB + wv * 32 + ni * 16 + l15;
        const float bval = z ? bias[col] : 0.0f;
        #pragma unroll
        for (int mi = 0; mi < 2; ++mi) {
            #pragma unroll
            for (int r = 0; r < 4; ++r) {
                const int row = rowB + mi * 16 + kh * 4 + r;
                C[(size_t)row * nEd + col] =
                    __builtin_amdgcn_exp2f((acc[mi][ni][r] + bval) * PRESCALE);
            }
        }
    }
}

// ---- kLogits: 2-t factored-sigmoid, 8 waves/SIMD, SW-pipelined ----------
// Grid (64 tg, 4 sg, 16 b), 4 waves. Wave w: s in [sg*32+w*8, +8),
// t in {tg*2, tg*2+1}. Low VGPR (<=64 forced) doubles occupancy vs r14.
__global__ __launch_bounds__(256, 8) void kLogits(
    const float* __restrict__ X1e,  // [B*S,E] exp2'd
    const float* __restrict__ X2e,  // [B*T,E] exp2'd (bias folded)
    const float* __restrict__ V,    // [E]
    float* __restrict__ lg)         // [B*T,S]
{
    const int tg = blockIdx.x, sg = blockIdx.y, b = blockIdx.z;
    const int tid  = threadIdx.x;
    const int lane = tid & 63;
    const int w    = tid >> 6;
    const int s0 = sg * 32 + w * 8;
    const int t0 = tg * 2;

    const float4* vp = (const float4*)V;
    float4 n0 = vp[lane * 2], n1 = vp[lane * 2 + 1];
    n0.x *= -2.f; n0.y *= -2.f; n0.z *= -2.f; n0.w *= -2.f;
    n1.x *= -2.f; n1.y *= -2.f; n1.z *= -2.f; n1.w *= -2.f;

    float4 c0[2], c1[2];
    #pragma unroll
    for (int i = 0; i < 2; ++i) {
        const float4* xp = (const float4*)(X2e + ((size_t)b * nTq + t0 + i) * nEd);
        c0[i] = xp[lane * 2];
        c1[i] = xp[lane * 2 + 1];
    }

    const float* X1b = X1e + (size_t)b * nSq * nEd;
    float4 x0 = ((const float4*)(X1b + (size_t)s0 * nEd))[lane * 2];
    float4 x1 = ((const float4*)(X1b + (size_t)s0 * nEd))[lane * 2 + 1];

    #pragma unroll
    for (int si = 0; si < 8; ++si) {
        const float4 cx0 = x0, cx1 = x1;
        if (si < 7) {   // software-pipeline next row
            const float4* np = (const float4*)(X1b + (size_t)(s0 + si + 1) * nEd);
            x0 = np[lane * 2];
            x1 = np[lane * 2 + 1];
        }
        float a0, a1;
        a0  = n0.x * __builtin_amdgcn_rcpf(cx0.x * c0[0].x + 1.0f);
        a1  = n0.x * __builtin_amdgcn_rcpf(cx0.x * c0[1].x + 1.0f);
        a0 += n0.y * __builtin_amdgcn_rcpf(cx0.y * c0[0].y + 1.0f);
        a1 += n0.y * __builtin_amdgcn_rcpf(cx0.y * c0[1].y + 1.0f);
        a0 += n0.z * __builtin_amdgcn_rcpf(cx0.z * c0[0].z + 1.0f);
        a1 += n0.z * __builtin_amdgcn_rcpf(cx0.z * c0[1].z + 1.0f);
        a0 += n0.w * __builtin_amdgcn_rcpf(cx0.w * c0[0].w + 1.0f);
        a1 += n0.w * __builtin_amdgcn_rcpf(cx0.w * c0[1].w + 1.0f);
        a0 += n1.x * __builtin_amdgcn_rcpf(cx1.x * c1[0].x + 1.0f);
        a1 += n1.x * __builtin_amdgcn_rcpf(cx1.x * c1[1].x + 1.0f);
        a0 += n1.y * __builtin_amdgcn_rcpf(cx1.y * c1[0].y + 1.0f);
        a1 += n1.y * __builtin_amdgcn_rcpf(cx1.y * c1[1].y + 1.0f);
        a0 += n1.z * __builtin_amdgcn_rcpf(cx1.z * c1[0].z + 1.0f);
        a1 += n1.z * __builtin_amdgcn_rcpf(cx1.z * c1[1].z + 1.0f);
        a0 += n1.w * __builtin_amdgcn_rcpf(cx1.w * c1[0].w + 1.0f);
        a1 += n1.w * __builtin_amdgcn_rcpf(cx1.w * c1[1].w + 1.0f);

        // 7-shuffle reduce: even lanes end with t0 sum, odd with t1 sum
        const float p0 = a0 + __shfl_xor(a0, 1);
        const float p1 = a1 + __shfl_xor(a1, 1);
        float q = (lane & 1) ? p1 : p0;
        q += __shfl_xor(q, 2);
        q += __shfl_xor(q, 4);
        q += __shfl_xor(q, 8);
        q += __shfl_xor(q, 16);
        q += __shfl_xor(q, 32);
        if (lane < 2)
            lg[((size_t)b * nTq + t0 + lane) * nSq + s0 + si] = q;
    }
}

// ---- kSoftW: softmax per (b,t), f32 weights in-place (r13-proven) -------
__global__ __launch_bounds__(256) void kSoftW(float* __restrict__ attnw)
{
    const int bt = blockIdx.x * 4 + (threadIdx.x >> 6);
    const int lane = threadIdx.x & 63;
    const float l0 = attnw[(size_t)bt * nSq + lane];
    const float l1 = attnw[(size_t)bt * nSq + lane + 64];
    float m = fmaxf(l0, l1);
    #pragma unroll
    for (int off = 32; off >= 1; off >>= 1)
        m = fmaxf(m, __shfl_xor(m, off));
    const float e0 = __builtin_amdgcn_exp2f((l0 - m) * LOG2E);
    const float e1 = __builtin_amdgcn_exp2f((l1 - m) * LOG2E);
    float sum = e0 + e1;
    #pragma unroll
    for (int off = 32; off >= 1; off >>= 1)
        sum += __shfl_xor(sum, off);
    const float inv = __builtin_amdgcn_rcpf(sum);
    attnw[(size_t)bt * nSq + lane]      = e0 * inv;
    attnw[(size_t)bt * nSq + lane + 64] = e1 * inv;
}

// ---- kCtxMM: ctx[b] = bf16(attnw[b]) @ encT[b]^T (r13-proven) -----------
__global__ __launch_bounds__(256) void kCtxMM(
    const float* __restrict__ attnw,          // [B*T,S] f32 weights
    const unsigned short* __restrict__ encT,  // [B*E,S]
    float* __restrict__ ctx)                  // [B*T,E]
{
    const int b  = blockIdx.z;
    const int tB = blockIdx.y * 32;
    const int eB = blockIdx.x * 64;

    __shared__ unsigned short sA[32][136];
    __shared__ unsigned short sB[64][136];

    const int tid  = threadIdx.x;
    const int lane = tid & 63;
    const int w    = tid >> 6;
    const int wm = (w >> 1) * 16;
    const int wn = (w & 1) * 32;
    const int l15 = lane & 15;
    const int kh  = lane >> 4;

    {   // stage A: convert 32x128 f32 weights -> bf16 (16/thread)
        const int r = tid >> 3, c = (tid & 7) * 16;
        const float* ap = &attnw[((size_t)b * nTq + tB + r) * nSq + c];
        unsigned short h[16];
        #pragma unroll
        for (int q = 0; q < 4; ++q) {
            const float4 v = *(const float4*)(ap + 4 * q);
            h[4 * q + 0] = to_bf(v.x); h[4 * q + 1] = to_bf(v.y);
            h[4 * q + 2] = to_bf(v.z); h[4 * q + 3] = to_bf(v.w);
        }
        *(s16x8*)&sA[r][c]     = *(s16x8*)&h[0];
        *(s16x8*)&sA[r][c + 8] = *(s16x8*)&h[8];
    }
    {   // stage B: 64x128 ushorts (32/thread)
        const int r = tid >> 2, c = (tid & 3) * 32;
        const size_t o = ((size_t)b * nEd + eB + r) * nSq + c;
        *(s16x8*)&sB[r][c]      = *(const s16x8*)&encT[o];
        *(s16x8*)&sB[r][c + 8]  = *(const s16x8*)&encT[o + 8];
        *(s16x8*)&sB[r][c + 16] = *(const s16x8*)&encT[o + 16];
        *(s16x8*)&sB[r][c + 24] = *(const s16x8*)&encT[o + 24];
    }
    __syncthreads();

    f32x4 acc[2] = {};
    #pragma unroll
    for (int kk = 0; kk < 4; ++kk) {
        const s16x8 fA = *(const s16x8*)&sA[wm + l15][kk * 32 + kh * 8];
        #pragma unroll
        for (int ni = 0; ni < 2; ++ni) {
            const s16x8 fB = *(const s16x8*)&sB[wn + ni * 16 + l15][kk * 32 + kh * 8];
            acc[ni] = __builtin_amdgcn_mfma_f32_16x16x32_bf16(fA, fB, acc[ni], 0, 0, 0);
        }
    }

    #pragma unroll
    for (int ni = 0; ni < 2; ++ni) {
        const int e = eB + wn + ni * 16 + l15;
        #pragma unroll
        for (int r = 0; r < 4; ++r) {
            const int t = tB + wm + kh * 4 + r;
            ctx[((size_t)b * nTq + t) * nEd + e] = acc[ni][r];
        }
    }
}

extern "C" void kernel_launch(void* const* d_in, const int* in_sizes, int n_in,
                              void* d_out, int out_size, void* d_ws, size_t ws_size,
                              hipStream_t stream) {
    const float* enc = (const float*)d_in[0];   // [16,128,512]
    const float* dec = (const float*)d_in[1];   // [16,128,512]
    const float* W1  = (const float*)d_in[2];   // [512,512]
    const float* W2  = (const float*)d_in[3];   // [512,512]
    const float* bv  = (const float*)d_in[4];   // [512]
    const float* V   = (const float*)d_in[5];   // [512]

    float* ctx   = (float*)d_out;                           // [16,128,512] 4MB
    float* attnw = (float*)d_out + (size_t)nBt * nTq * nEd; // [16,128,128] 1MB

    // WT (2MB) in ctx region — dead before kCtxMM writes ctx.
    unsigned short* WT = (unsigned short*)d_out;

    float* ws0 = (float*)d_ws;                    // exp2((enc@W1)*PS), 4MB
    float* ws1 = ws0 + (size_t)nBt * nSq * nEd;   // exp2((dec@W2+b)*PS), 4MB

    const size_t eight_mb = (size_t)8 * 1024 * 1024;
    const bool early = ws_size >= eight_mb + (size_t)2 * 1024 * 1024 + 4096;
    unsigned short* encT = early
        ? (unsigned short*)((char*)d_ws + eight_mb)
        : (unsigned short*)d_ws;

    if (early) {
        kPrep<<<dim3(1536), dim3(256), 0, stream>>>(W1, W2, WT, enc, encT);
        kMgemmB<<<dim3(nEd / 128, (nBt * nSq) / 32, 2), dim3(256), 0, stream>>>(
            enc, dec, WT, bv, ws0, ws1);
        kLogits<<<dim3(nTq / 2, 4, nBt), dim3(256), 0, stream>>>(ws0, ws1, V, attnw);
    } else {
        kPrep<<<dim3(512), dim3(256), 0, stream>>>(W1, W2, WT, enc, encT);
        kMgemmB<<<dim3(nEd / 128, (nBt * nSq) / 32, 2), dim3(256), 0, stream>>>(
            enc, dec, WT, bv, ws0, ws1);
        kLogits<<<dim3(nTq / 2, 4, nBt), dim3(256), 0, stream>>>(ws0, ws1, V, attnw);
        kEncT<<<dim3(nEd / 32, nSq / 32, nBt), dim3(256), 0, stream>>>(enc, encT);
    }
    kSoftW<<<dim3((nBt * nTq) / 4), dim3(256), 0, stream>>>(attnw);
    kCtxMM<<<dim3(nEd / 64, nTq / 32, nBt), dim3(256), 0, stream>>>(
        attnw, encT, ctx);
}

// Round 16
// 51.132 us; speedup vs baseline: 1.0246x; 1.0246x over previous
//
#include <hip/hip_runtime.h>
#include <hip/hip_bf16.h>
#include <cstddef>

// Pipeline (4 launches in early path, 5 in fallback):
//  kPrep   : W split-bf16 transpose (+ encT transpose when ws has room)
//  kMgemmB : split-bf16 3-term MFMA GEMM, 32x128 tile; epilogue stores
//            exp2 of prescaled activation (factored sigmoid)
//  kLogSm  : factored-sigmoid scores with PAIRWISE-RCP (1 trans / 2 elems;
//            r15 showed trans-pipe floor, not occupancy/BW) + fused softmax
//            (block owns full 128-s rows for a t-pair) -> final weights
//  kEncT   : standalone fallback when encT must reuse X1e space
//  kCtxMM  : MFMA batched context GEMM, f32->bf16 weights in A-staging

constexpr int nBt = 16, nSq = 128, nTq = 128, nEd = 512;

typedef __attribute__((ext_vector_type(4))) float f32x4;
typedef __attribute__((ext_vector_type(8))) short s16x8;

#define PRESCALE 2.8853900817779268f  /* 2*log2(e) */
#define LOG2E 1.4426950408889634f

__device__ __forceinline__ unsigned short to_bf(float f) {
    unsigned u = __builtin_bit_cast(unsigned, f);
    return (unsigned short)((u + 0x7FFFu + ((u >> 16) & 1u)) >> 16);  // RNE
}
__device__ __forceinline__ float from_bf(unsigned short h) {
    unsigned u = ((unsigned)h) << 16;
    return __builtin_bit_cast(float, u);
}

// n_a/A + n_b/B accumulated with ONE rcp: (n_a*B + n_b*A) * rcp(A*B)
__device__ __forceinline__ void pair_acc(
    float xa, float xb, float ca, float cb, float na, float nb, float& acc)
{
    const float A = fmaf(xa, ca, 1.0f);
    const float B = fmaf(xb, cb, 1.0f);
    const float r = __builtin_amdgcn_rcpf(A * B);
    float num = na * B;
    num = fmaf(nb, A, num);
    acc = fmaf(num, r, acc);
}

// ---- kPrep: [0,512) W-split blocks; [512,1536) encT blocks (if early) ---
__global__ __launch_bounds__(256) void kPrep(
    const float* __restrict__ W1, const float* __restrict__ W2,
    unsigned short* __restrict__ WT,
    const float* __restrict__ enc, unsigned short* __restrict__ encT)
{
    __shared__ float tl[32][33];
    const int r  = threadIdx.x >> 3;
    const int c4 = (threadIdx.x & 7) * 4;
    int bid = blockIdx.x;

    if (bid < 512) {   // W split-transpose (r8-proven math)
        const int z = bid >> 8;
        const int yx = bid & 255;
        const int kB = (yx >> 4) * 32;
        const int nB = (yx & 15) * 32;
        const float* W = z ? W2 : W1;
        const float4 v = *(const float4*)&W[(size_t)(kB + r) * nEd + nB + c4];
        tl[r][c4 + 0] = v.x; tl[r][c4 + 1] = v.y;
        tl[r][c4 + 2] = v.z; tl[r][c4 + 3] = v.w;
        __syncthreads();
        unsigned short hh[4], ll[4];
        #pragma unroll
        for (int i = 0; i < 4; ++i) {
            const float x = tl[c4 + i][r];
            hh[i] = to_bf(x);
            ll[i] = to_bf(x - from_bf(hh[i]));
        }
        const size_t o = ((size_t)z * nEd + nB + r) * nEd + kB + c4;
        *(ushort4*)&WT[o] = *(ushort4*)hh;
        *(ushort4*)&WT[(size_t)2 * nEd * nEd + o] = *(ushort4*)ll;
    } else {           // encT transpose (r9-proven math)
        bid -= 512;
        const int b = bid >> 6;
        const int r6 = bid & 63;
        const int eB = (r6 & 15) * 32;
        const int sB = (r6 >> 4) * 32;
        const float4 v = *(const float4*)&enc[((size_t)b * nSq + sB + r) * nEd + eB + c4];
        tl[r][c4 + 0] = v.x; tl[r][c4 + 1] = v.y;
        tl[r][c4 + 2] = v.z; tl[r][c4 + 3] = v.w;
        __syncthreads();
        unsigned short o[4];
        #pragma unroll
        for (int i = 0; i < 4; ++i) o[i] = to_bf(tl[c4 + i][r]);
        *(ushort4*)&encT[((size_t)b * nEd + eB + r) * nSq + sB + c4] = *(ushort4*)o;
    }
}

// ---- kEncT: standalone fallback (r9-proven) -----------------------------
__global__ __launch_bounds__(256) void kEncT(
    const float* __restrict__ enc, unsigned short* __restrict__ encT)
{
    const int b = blockIdx.z;
    __shared__ float tl[32][33];
    const int r  = threadIdx.x >> 3;
    const int c4 = (threadIdx.x & 7) * 4;
    const int sB = blockIdx.y * 32;
    const int eB = blockIdx.x * 32;
    const float4 v = *(const float4*)&enc[((size_t)b * nSq + sB + r) * nEd + eB + c4];
    tl[r][c4 + 0] = v.x; tl[r][c4 + 1] = v.y;
    tl[r][c4 + 2] = v.z; tl[r][c4 + 3] = v.w;
    __syncthreads();
    unsigned short o[4];
    #pragma unroll
    for (int i = 0; i < 4; ++i) o[i] = to_bf(tl[c4 + i][r]);
    *(ushort4*)&encT[((size_t)b * nEd + eB + r) * nSq + sB + c4] = *(ushort4*)o;
}

// ---- kMgemmB: C_z = exp2((A_z @ W_z [+bias]) * PRESCALE) (r11-15 proven)
__global__ __launch_bounds__(256) void kMgemmB(
    const float* __restrict__ A0, const float* __restrict__ A1,
    const unsigned short* __restrict__ WT, const float* __restrict__ bias,
    float* __restrict__ C0, float* __restrict__ C1)
{
    const int z = blockIdx.z;
    const float* __restrict__ A = z ? A1 : A0;
    const unsigned short* __restrict__ Wh = WT + (size_t)z * nEd * nEd;
    const unsigned short* __restrict__ Wl = Wh + (size_t)2 * nEd * nEd;
    float* __restrict__ C = z ? C1 : C0;

    __shared__ unsigned short sAh[32][72];
    __shared__ unsigned short sAl[32][72];
    __shared__ unsigned short sBh[128][72];
    __shared__ unsigned short sBl[128][72];

    const int tid  = threadIdx.x;
    const int lane = tid & 63;
    const int wv   = tid >> 6;
    const int rowB = blockIdx.y * 32;
    const int colB = blockIdx.x * 128;

    const int ar = tid >> 3, ak = (tid & 7) * 8;
    const int br = tid >> 1, bc = (tid & 1) * 32;

    f32x4 acc[2][2] = {};
    const int l15 = lane & 15;
    const int kh  = lane >> 4;

    for (int k0 = 0; k0 < nEd; k0 += 64) {
        const float4 ga0 = *(const float4*)&A[(size_t)(rowB + ar) * nEd + k0 + ak];
        const float4 ga1 = *(const float4*)&A[(size_t)(rowB + ar) * nEd + k0 + ak + 4];
        const size_t wo = (size_t)(colB + br) * nEd + k0 + bc;
        s16x8 gh[4], gl[4];
        #pragma unroll
        for (int j = 0; j < 4; ++j) {
            gh[j] = *(const s16x8*)&Wh[wo + 8 * j];
            gl[j] = *(const s16x8*)&Wl[wo + 8 * j];
        }

        __syncthreads();
        {
            const float a8[8] = {ga0.x, ga0.y, ga0.z, ga0.w,
                                 ga1.x, ga1.y, ga1.z, ga1.w};
            unsigned short h[8], l[8];
            #pragma unroll
            for (int i = 0; i < 8; ++i) {
                h[i] = to_bf(a8[i]);
                l[i] = to_bf(a8[i] - from_bf(h[i]));
            }
            *(ushort4*)&sAh[ar][ak]     = *(ushort4*)&h[0];
            *(ushort4*)&sAh[ar][ak + 4] = *(ushort4*)&h[4];
            *(ushort4*)&sAl[ar][ak]     = *(ushort4*)&l[0];
            *(ushort4*)&sAl[ar][ak + 4] = *(ushort4*)&l[4];
        }
        #pragma unroll
        for (int j = 0; j < 4; ++j) {
            *(s16x8*)&sBh[br][bc + 8 * j] = gh[j];
            *(s16x8*)&sBl[br][bc + 8 * j] = gl[j];
        }
        __syncthreads();

        #pragma unroll
        for (int kk = 0; kk < 2; ++kk) {
            s16x8 fAh[2], fAl[2], fBh[2], fBl[2];
            #pragma unroll
            for (int mi = 0; mi < 2; ++mi) {
                fAh[mi] = *(const s16x8*)&sAh[mi * 16 + l15][kk * 32 + kh * 8];
                fAl[mi] = *(const s16x8*)&sAl[mi * 16 + l15][kk * 32 + kh * 8];
            }
            #pragma unroll
            for (int ni = 0; ni < 2; ++ni) {
                fBh[ni] = *(const s16x8*)&sBh[wv * 32 + ni * 16 + l15][kk * 32 + kh * 8];
                fBl[ni] = *(const s16x8*)&sBl[wv * 32 + ni * 16 + l15][kk * 32 + kh * 8];
            }
            #pragma unroll
            for (int mi = 0; mi < 2; ++mi)
                #pragma unroll
                for (int ni = 0; ni < 2; ++ni) {
                    f32x4 a = acc[mi][ni];
                    a = __builtin_amdgcn_mfma_f32_16x16x32_bf16(fAh[mi], fBh[ni], a, 0, 0, 0);
                    a = __builtin_amdgcn_mfma_f32_16x16x32_bf16(fAl[mi], fBh[ni], a, 0, 0, 0);
                    a = __builtin_amdgcn_mfma_f32_16x16x32_bf16(fAh[mi], fBl[ni], a, 0, 0, 0);
                    acc[mi][ni] = a;
                }
        }
    }

    #pragma unroll
    for (int ni = 0; ni < 2; ++ni) {
        const int col = colB + wv * 32 + ni * 16 + l15;
        const float bval = z ? bias[col] : 0.0f;
        #pragma unroll
        for (int mi = 0; mi < 2; ++mi) {
            #pragma unroll
            for (int r = 0; r < 4; ++r) {
                const int row = rowB + mi * 16 + kh * 4 + r;
                C[(size_t)row * nEd + col] =
                    __builtin_amdgcn_exp2f((acc[mi][ni][r] + bval) * PRESCALE);
            }
        }
    }
}

// ---- kLogSm: pairwise-rcp logits + fused softmax ------------------------
// Grid (T/2=64, B=16), 4 waves. Block owns t-pair {tg*2, tg*2+1} over ALL
// 128 s. Wave w covers s in [w*32, w*32+32). Logits -> LDS; softmax
// (waves 0,1, one t-row each) writes final weights to attnw.
__global__ __launch_bounds__(256) void kLogSm(
    const float* __restrict__ X1e,  // [B*S,E] exp2'd
    const float* __restrict__ X2e,  // [B*T,E] exp2'd (bias folded)
    const float* __restrict__ V,    // [E]
    float* __restrict__ attnw)      // [B*T,S] out: softmax weights
{
    const int tg = blockIdx.x, b = blockIdx.y;
    const int tid  = threadIdx.x;
    const int lane = tid & 63;
    const int w    = tid >> 6;
    const int s0 = w * 32;
    const int t0 = tg * 2;

    __shared__ float sm[2][nSq];

    const float4* vp = (const float4*)V;
    float4 n0 = vp[lane * 2], n1 = vp[lane * 2 + 1];
    n0.x *= -2.f; n0.y *= -2.f; n0.z *= -2.f; n0.w *= -2.f;
    n1.x *= -2.f; n1.y *= -2.f; n1.z *= -2.f; n1.w *= -2.f;

    float4 c0[2], c1[2];
    #pragma unroll
    for (int i = 0; i < 2; ++i) {
        const float4* xp = (const float4*)(X2e + ((size_t)b * nTq + t0 + i) * nEd);
        c0[i] = xp[lane * 2];
        c1[i] = xp[lane * 2 + 1];
    }

    const float* X1b = X1e + (size_t)b * nSq * nEd;
    float4 x0 = ((const float4*)(X1b + (size_t)s0 * nEd))[lane * 2];
    float4 x1 = ((const float4*)(X1b + (size_t)s0 * nEd))[lane * 2 + 1];

    #pragma unroll 4
    for (int si = 0; si < 32; ++si) {
        const float4 cx0 = x0, cx1 = x1;
        if (si < 31) {   // software-pipeline next row
            const float4* np = (const float4*)(X1b + (size_t)(s0 + si + 1) * nEd);
            x0 = np[lane * 2];
            x1 = np[lane * 2 + 1];
        }
        float a0 = 0.f, a1 = 0.f;
        // t0
        pair_acc(cx0.x, cx0.y, c0[0].x, c0[0].y, n0.x, n0.y, a0);
        pair_acc(cx0.z, cx0.w, c0[0].z, c0[0].w, n0.z, n0.w, a0);
        pair_acc(cx1.x, cx1.y, c1[0].x, c1[0].y, n1.x, n1.y, a0);
        pair_acc(cx1.z, cx1.w, c1[0].z, c1[0].w, n1.z, n1.w, a0);
        // t1
        pair_acc(cx0.x, cx0.y, c0[1].x, c0[1].y, n0.x, n0.y, a1);
        pair_acc(cx0.z, cx0.w, c0[1].z, c0[1].w, n0.z, n0.w, a1);
        pair_acc(cx1.x, cx1.y, c1[1].x, c1[1].y, n1.x, n1.y, a1);
        pair_acc(cx1.z, cx1.w, c1[1].z, c1[1].w, n1.z, n1.w, a1);

        // 7-shuffle reduce: even lanes end with t0 sum, odd with t1 sum
        const float p0 = a0 + __shfl_xor(a0, 1);
        const float p1 = a1 + __shfl_xor(a1, 1);
        float q = (lane & 1) ? p1 : p0;
        q += __shfl_xor(q, 2);
        q += __shfl_xor(q, 4);
        q += __shfl_xor(q, 8);
        q += __shfl_xor(q, 16);
        q += __shfl_xor(q, 32);
        if (lane < 2) sm[lane][s0 + si] = q;
    }
    __syncthreads();

    // softmax: wave w < 2 handles t-row t0 + w (r13-proven body)
    if (w < 2) {
        const float l0 = sm[w][lane], l1 = sm[w][lane + 64];
        float m = fmaxf(l0, l1);
        #pragma unroll
        for (int off = 32; off >= 1; off >>= 1)
            m = fmaxf(m, __shfl_xor(m, off));
        const float e0 = __builtin_amdgcn_exp2f((l0 - m) * LOG2E);
        const float e1 = __builtin_amdgcn_exp2f((l1 - m) * LOG2E);
        float sum = e0 + e1;
        #pragma unroll
        for (int off = 32; off >= 1; off >>= 1)
            sum += __shfl_xor(sum, off);
        const float inv = __builtin_amdgcn_rcpf(sum);
        float* ap = attnw + ((size_t)b * nTq + t0 + w) * nSq;
        ap[lane]      = e0 * inv;
        ap[lane + 64] = e1 * inv;
    }
}

// ---- kCtxMM: ctx[b] = bf16(attnw[b]) @ encT[b]^T (r13-proven) -----------
__global__ __launch_bounds__(256) void kCtxMM(
    const float* __restrict__ attnw,          // [B*T,S] f32 weights
    const unsigned short* __restrict__ encT,  // [B*E,S]
    float* __restrict__ ctx)                  // [B*T,E]
{
    const int b  = blockIdx.z;
    const int tB = blockIdx.y * 32;
    const int eB = blockIdx.x * 64;

    __shared__ unsigned short sA[32][136];
    __shared__ unsigned short sB[64][136];

    const int tid  = threadIdx.x;
    const int lane = tid & 63;
    const int w    = tid >> 6;
    const int wm = (w >> 1) * 16;
    const int wn = (w & 1) * 32;
    const int l15 = lane & 15;
    const int kh  = lane >> 4;

    {   // stage A: convert 32x128 f32 weights -> bf16 (16/thread)
        const int r = tid >> 3, c = (tid & 7) * 16;
        const float* ap = &attnw[((size_t)b * nTq + tB + r) * nSq + c];
        unsigned short h[16];
        #pragma unroll
        for (int q = 0; q < 4; ++q) {
            const float4 v = *(const float4*)(ap + 4 * q);
            h[4 * q + 0] = to_bf(v.x); h[4 * q + 1] = to_bf(v.y);
            h[4 * q + 2] = to_bf(v.z); h[4 * q + 3] = to_bf(v.w);
        }
        *(s16x8*)&sA[r][c]     = *(s16x8*)&h[0];
        *(s16x8*)&sA[r][c + 8] = *(s16x8*)&h[8];
    }
    {   // stage B: 64x128 ushorts (32/thread)
        const int r = tid >> 2, c = (tid & 3) * 32;
        const size_t o = ((size_t)b * nEd + eB + r) * nSq + c;
        *(s16x8*)&sB[r][c]      = *(const s16x8*)&encT[o];
        *(s16x8*)&sB[r][c + 8]  = *(const s16x8*)&encT[o + 8];
        *(s16x8*)&sB[r][c + 16] = *(const s16x8*)&encT[o + 16];
        *(s16x8*)&sB[r][c + 24] = *(const s16x8*)&encT[o + 24];
    }
    __syncthreads();

    f32x4 acc[2] = {};
    #pragma unroll
    for (int kk = 0; kk < 4; ++kk) {
        const s16x8 fA = *(const s16x8*)&sA[wm + l15][kk * 32 + kh * 8];
        #pragma unroll
        for (int ni = 0; ni < 2; ++ni) {
            const s16x8 fB = *(const s16x8*)&sB[wn + ni * 16 + l15][kk * 32 + kh * 8];
            acc[ni] = __builtin_amdgcn_mfma_f32_16x16x32_bf16(fA, fB, acc[ni], 0, 0, 0);
        }
    }

    #pragma unroll
    for (int ni = 0; ni < 2; ++ni) {
        const int e = eB + wn + ni * 16 + l15;
        #pragma unroll
        for (int r = 0; r < 4; ++r) {
            const int t = tB + wm + kh * 4 + r;
            ctx[((size_t)b * nTq + t) * nEd + e] = acc[ni][r];
        }
    }
}

extern "C" void kernel_launch(void* const* d_in, const int* in_sizes, int n_in,
                              void* d_out, int out_size, void* d_ws, size_t ws_size,
                              hipStream_t stream) {
    const float* enc = (const float*)d_in[0];   // [16,128,512]
    const float* dec = (const float*)d_in[1];   // [16,128,512]
    const float* W1  = (const float*)d_in[2];   // [512,512]
    const float* W2  = (const float*)d_in[3];   // [512,512]
    const float* bv  = (const float*)d_in[4];   // [512]
    const float* V   = (const float*)d_in[5];   // [512]

    float* ctx   = (float*)d_out;                           // [16,128,512] 4MB
    float* attnw = (float*)d_out + (size_t)nBt * nTq * nEd; // [16,128,128] 1MB

    // WT (2MB) in ctx region — dead before kCtxMM writes ctx.
    unsigned short* WT = (unsigned short*)d_out;

    float* ws0 = (float*)d_ws;                    // exp2((enc@W1)*PS), 4MB
    float* ws1 = ws0 + (size_t)nBt * nSq * nEd;   // exp2((dec@W2+b)*PS), 4MB

    const size_t eight_mb = (size_t)8 * 1024 * 1024;
    const bool early = ws_size >= eight_mb + (size_t)2 * 1024 * 1024 + 4096;
    unsigned short* encT = early
        ? (unsigned short*)((char*)d_ws + eight_mb)
        : (unsigned short*)d_ws;

    if (early) {
        kPrep<<<dim3(1536), dim3(256), 0, stream>>>(W1, W2, WT, enc, encT);
        kMgemmB<<<dim3(nEd / 128, (nBt * nSq) / 32, 2), dim3(256), 0, stream>>>(
            enc, dec, WT, bv, ws0, ws1);
        kLogSm<<<dim3(nTq / 2, nBt), dim3(256), 0, stream>>>(ws0, ws1, V, attnw);
    } else {
        kPrep<<<dim3(512), dim3(256), 0, stream>>>(W1, W2, WT, enc, encT);
        kMgemmB<<<dim3(nEd / 128, (nBt * nSq) / 32, 2), dim3(256), 0, stream>>>(
            enc, dec, WT, bv, ws0, ws1);
        kLogSm<<<dim3(nTq / 2, nBt), dim3(256), 0, stream>>>(ws0, ws1, V, attnw);
        kEncT<<<dim3(nEd / 32, nSq / 32, nBt), dim3(256), 0, stream>>>(enc, encT);
    }
    kCtxMM<<<dim3(nEd / 64, nTq / 32, nBt), dim3(256), 0, stream>>>(
        attnw, encT, ctx);
}

// Round 17
// 50.438 us; speedup vs baseline: 1.0388x; 1.0138x over previous
//
#include <hip/hip_runtime.h>
#include <hip/hip_bf16.h>
#include <cstddef>

// Pipeline (4 launches, early path):
//  kPrep   : W split-transpose + encT transpose + A(enc,dec) split-bf16
//            pre-pass (hoists ~80 VALU/iter out of the GEMM hot loop)
//  kMgemmC : split-bf16 3-term MFMA GEMM, 32x128 tile, staging = PURE
//            s16x8 copies (no conversion VALU); epilogue stores exp2
//  kLogSm  : pairwise-rcp logits + fused softmax (r16-proven)
//  kCtxMM  : MFMA batched context GEMM (r13-proven)
// Fallback (ws too small): r16 path with in-loop split (kMgemmB).

constexpr int nBt = 16, nSq = 128, nTq = 128, nEd = 512;

typedef __attribute__((ext_vector_type(4))) float f32x4;
typedef __attribute__((ext_vector_type(8))) short s16x8;

#define PRESCALE 2.8853900817779268f  /* 2*log2(e) */
#define LOG2E 1.4426950408889634f

__device__ __forceinline__ unsigned short to_bf(float f) {
    unsigned u = __builtin_bit_cast(unsigned, f);
    return (unsigned short)((u + 0x7FFFu + ((u >> 16) & 1u)) >> 16);  // RNE
}
__device__ __forceinline__ float from_bf(unsigned short h) {
    unsigned u = ((unsigned)h) << 16;
    return __builtin_bit_cast(float, u);
}

// n_a/A + n_b/B with ONE rcp: (n_a*B + n_b*A) * rcp(A*B)
__device__ __forceinline__ void pair_acc(
    float xa, float xb, float ca, float cb, float na, float nb, float& acc)
{
    const float A = fmaf(xa, ca, 1.0f);
    const float B = fmaf(xb, cb, 1.0f);
    const float r = __builtin_amdgcn_rcpf(A * B);
    float num = na * B;
    num = fmaf(nb, A, num);
    acc = fmaf(num, r, acc);
}

// ---- kPrep: [0,512) W-split; [512,1536) encT; [1536,2560) A-split -------
__global__ __launch_bounds__(256) void kPrep(
    const float* __restrict__ W1, const float* __restrict__ W2,
    unsigned short* __restrict__ WT,
    const float* __restrict__ enc, const float* __restrict__ dec,
    unsigned short* __restrict__ encT,
    unsigned short* __restrict__ Ah, unsigned short* __restrict__ Al)
{
    __shared__ float tl[32][33];
    const int r  = threadIdx.x >> 3;
    const int c4 = (threadIdx.x & 7) * 4;
    int bid = blockIdx.x;

    if (bid < 512) {   // W split-transpose (r8-proven)
        const int z = bid >> 8;
        const int yx = bid & 255;
        const int kB = (yx >> 4) * 32;
        const int nB = (yx & 15) * 32;
        const float* W = z ? W2 : W1;
        const float4 v = *(const float4*)&W[(size_t)(kB + r) * nEd + nB + c4];
        tl[r][c4 + 0] = v.x; tl[r][c4 + 1] = v.y;
        tl[r][c4 + 2] = v.z; tl[r][c4 + 3] = v.w;
        __syncthreads();
        unsigned short hh[4], ll[4];
        #pragma unroll
        for (int i = 0; i < 4; ++i) {
            const float x = tl[c4 + i][r];
            hh[i] = to_bf(x);
            ll[i] = to_bf(x - from_bf(hh[i]));
        }
        const size_t o = ((size_t)z * nEd + nB + r) * nEd + kB + c4;
        *(ushort4*)&WT[o] = *(ushort4*)hh;
        *(ushort4*)&WT[(size_t)2 * nEd * nEd + o] = *(ushort4*)ll;
    } else if (bid < 1536) {   // encT transpose (r9-proven)
        bid -= 512;
        const int b = bid >> 6;
        const int r6 = bid & 63;
        const int eB = (r6 & 15) * 32;
        const int sB = (r6 >> 4) * 32;
        const float4 v = *(const float4*)&enc[((size_t)b * nSq + sB + r) * nEd + eB + c4];
        tl[r][c4 + 0] = v.x; tl[r][c4 + 1] = v.y;
        tl[r][c4 + 2] = v.z; tl[r][c4 + 3] = v.w;
        __syncthreads();
        unsigned short o[4];
        #pragma unroll
        for (int i = 0; i < 4; ++i) o[i] = to_bf(tl[c4 + i][r]);
        *(ushort4*)&encT[((size_t)b * nEd + eB + r) * nSq + sB + c4] = *(ushort4*)o;
    } else {   // A split pre-pass (streaming, no transpose)
        const size_t g0 = ((size_t)(bid - 1536) * 256 + threadIdx.x) * 8;
        const int z = (int)(g0 >> 20);            // 2048*512 = 2^20 per z
        const size_t rem = g0 & 0xFFFFFu;
        const float* A = z ? dec : enc;
        const float4 a0 = *(const float4*)&A[rem];
        const float4 a1 = *(const float4*)&A[rem + 4];
        const float a8[8] = {a0.x, a0.y, a0.z, a0.w, a1.x, a1.y, a1.z, a1.w};
        unsigned short h[8], l[8];
        #pragma unroll
        for (int i = 0; i < 8; ++i) {
            h[i] = to_bf(a8[i]);
            l[i] = to_bf(a8[i] - from_bf(h[i]));
        }
        *(ushort4*)&Ah[g0]     = *(ushort4*)&h[0];
        *(ushort4*)&Ah[g0 + 4] = *(ushort4*)&h[4];
        *(ushort4*)&Al[g0]     = *(ushort4*)&l[0];
        *(ushort4*)&Al[g0 + 4] = *(ushort4*)&l[4];
    }
}

// ---- kMgemmC: exp2((A @ W [+bias]) * PS); staging = pure copies ---------
__global__ __launch_bounds__(256) void kMgemmC(
    const unsigned short* __restrict__ Ah, const unsigned short* __restrict__ Al,
    const unsigned short* __restrict__ WT, const float* __restrict__ bias,
    float* __restrict__ C0, float* __restrict__ C1)
{
    const int z = blockIdx.z;
    const unsigned short* __restrict__ Ahz = Ah + ((size_t)z << 20);
    const unsigned short* __restrict__ Alz = Al + ((size_t)z << 20);
    const unsigned short* __restrict__ Wh = WT + (size_t)z * nEd * nEd;
    const unsigned short* __restrict__ Wl = Wh + (size_t)2 * nEd * nEd;
    float* __restrict__ C = z ? C1 : C0;

    __shared__ unsigned short sAh[32][72];
    __shared__ unsigned short sAl[32][72];
    __shared__ unsigned short sBh[128][72];
    __shared__ unsigned short sBl[128][72];

    const int tid  = threadIdx.x;
    const int lane = tid & 63;
    const int wv   = tid >> 6;
    const int rowB = blockIdx.y * 32;
    const int colB = blockIdx.x * 128;

    const int ar = tid >> 3, ak = (tid & 3) * 8;    // note: tid&7 gives 8 slots,
    // but A-tile is 32x64 = 2048 elems/plane = 8/thread: ar in [0,32), ak via (tid&7)*8
    const int ar8 = tid >> 3, ak8 = (tid & 7) * 8;
    const int br = tid >> 1, bc = (tid & 1) * 32;

    f32x4 acc[2][2] = {};
    const int l15 = lane & 15;
    const int kh  = lane >> 4;

    for (int k0 = 0; k0 < nEd; k0 += 64) {
        const size_t ao = (size_t)(rowB + ar8) * nEd + k0 + ak8;
        const s16x8 gah = *(const s16x8*)&Ahz[ao];
        const s16x8 gal = *(const s16x8*)&Alz[ao];
        const size_t wo = (size_t)(colB + br) * nEd + k0 + bc;
        s16x8 gh[4], gl[4];
        #pragma unroll
        for (int j = 0; j < 4; ++j) {
            gh[j] = *(const s16x8*)&Wh[wo + 8 * j];
            gl[j] = *(const s16x8*)&Wl[wo + 8 * j];
        }

        __syncthreads();
        *(s16x8*)&sAh[ar8][ak8] = gah;
        *(s16x8*)&sAl[ar8][ak8] = gal;
        #pragma unroll
        for (int j = 0; j < 4; ++j) {
            *(s16x8*)&sBh[br][bc + 8 * j] = gh[j];
            *(s16x8*)&sBl[br][bc + 8 * j] = gl[j];
        }
        __syncthreads();

        #pragma unroll
        for (int kk = 0; kk < 2; ++kk) {
            s16x8 fAh[2], fAl[2], fBh[2], fBl[2];
            #pragma unroll
            for (int mi = 0; mi < 2; ++mi) {
                fAh[mi] = *(const s16x8*)&sAh[mi * 16 + l15][kk * 32 + kh * 8];
                fAl[mi] = *(const s16x8*)&sAl[mi * 16 + l15][kk * 32 + kh * 8];
            }
            #pragma unroll
            for (int ni = 0; ni < 2; ++ni) {
                fBh[ni] = *(const s16x8*)&sBh[wv * 32 + ni * 16 + l15][kk * 32 + kh * 8];
                fBl[ni] = *(const s16x8*)&sBl[wv * 32 + ni * 16 + l15][kk * 32 + kh * 8];
            }
            #pragma unroll
            for (int mi = 0; mi < 2; ++mi)
                #pragma unroll
                for (int ni = 0; ni < 2; ++ni) {
                    f32x4 a = acc[mi][ni];
                    a = __builtin_amdgcn_mfma_f32_16x16x32_bf16(fAh[mi], fBh[ni], a, 0, 0, 0);
                    a = __builtin_amdgcn_mfma_f32_16x16x32_bf16(fAl[mi], fBh[ni], a, 0, 0, 0);
                    a = __builtin_amdgcn_mfma_f32_16x16x32_bf16(fAh[mi], fBl[ni], a, 0, 0, 0);
                    acc[mi][ni] = a;
                }
        }
    }

    #pragma unroll
    for (int ni = 0; ni < 2; ++ni) {
        const int col = colB + wv * 32 + ni * 16 + l15;
        const float bval = z ? bias[col] : 0.0f;
        #pragma unroll
        for (int mi = 0; mi < 2; ++mi) {
            #pragma unroll
            for (int r = 0; r < 4; ++r) {
                const int row = rowB + mi * 16 + kh * 4 + r;
                C[(size_t)row * nEd + col] =
                    __builtin_amdgcn_exp2f((acc[mi][ni][r] + bval) * PRESCALE);
            }
        }
    }
    (void)ak; (void)ar;
}

// ---- kMgemmB: fallback with in-loop split (r11-16 proven) ---------------
__global__ __launch_bounds__(256) void kMgemmB(
    const float* __restrict__ A0, const float* __restrict__ A1,
    const unsigned short* __restrict__ WT, const float* __restrict__ bias,
    float* __restrict__ C0, float* __restrict__ C1)
{
    const int z = blockIdx.z;
    const float* __restrict__ A = z ? A1 : A0;
    const unsigned short* __restrict__ Wh = WT + (size_t)z * nEd * nEd;
    const unsigned short* __restrict__ Wl = Wh + (size_t)2 * nEd * nEd;
    float* __restrict__ C = z ? C1 : C0;

    __shared__ unsigned short sAh[32][72];
    __shared__ unsigned short sAl[32][72];
    __shared__ unsigned short sBh[128][72];
    __shared__ unsigned short sBl[128][72];

    const int tid  = threadIdx.x;
    const int lane = tid & 63;
    const int wv   = tid >> 6;
    const int rowB = blockIdx.y * 32;
    const int colB = blockIdx.x * 128;

    const int ar = tid >> 3, ak = (tid & 7) * 8;
    const int br = tid >> 1, bc = (tid & 1) * 32;

    f32x4 acc[2][2] = {};
    const int l15 = lane & 15;
    const int kh  = lane >> 4;

    for (int k0 = 0; k0 < nEd; k0 += 64) {
        const float4 ga0 = *(const float4*)&A[(size_t)(rowB + ar) * nEd + k0 + ak];
        const float4 ga1 = *(const float4*)&A[(size_t)(rowB + ar) * nEd + k0 + ak + 4];
        const size_t wo = (size_t)(colB + br) * nEd + k0 + bc;
        s16x8 gh[4], gl[4];
        #pragma unroll
        for (int j = 0; j < 4; ++j) {
            gh[j] = *(const s16x8*)&Wh[wo + 8 * j];
            gl[j] = *(const s16x8*)&Wl[wo + 8 * j];
        }

        __syncthreads();
        {
            const float a8[8] = {ga0.x, ga0.y, ga0.z, ga0.w,
                                 ga1.x, ga1.y, ga1.z, ga1.w};
            unsigned short h[8], l[8];
            #pragma unroll
            for (int i = 0; i < 8; ++i) {
                h[i] = to_bf(a8[i]);
                l[i] = to_bf(a8[i] - from_bf(h[i]));
            }
            *(ushort4*)&sAh[ar][ak]     = *(ushort4*)&h[0];
            *(ushort4*)&sAh[ar][ak + 4] = *(ushort4*)&h[4];
            *(ushort4*)&sAl[ar][ak]     = *(ushort4*)&l[0];
            *(ushort4*)&sAl[ar][ak + 4] = *(ushort4*)&l[4];
        }
        #pragma unroll
        for (int j = 0; j < 4; ++j) {
            *(s16x8*)&sBh[br][bc + 8 * j] = gh[j];
            *(s16x8*)&sBl[br][bc + 8 * j] = gl[j];
        }
        __syncthreads();

        #pragma unroll
        for (int kk = 0; kk < 2; ++kk) {
            s16x8 fAh[2], fAl[2], fBh[2], fBl[2];
            #pragma unroll
            for (int mi = 0; mi < 2; ++mi) {
                fAh[mi] = *(const s16x8*)&sAh[mi * 16 + l15][kk * 32 + kh * 8];
                fAl[mi] = *(const s16x8*)&sAl[mi * 16 + l15][kk * 32 + kh * 8];
            }
            #pragma unroll
            for (int ni = 0; ni < 2; ++ni) {
                fBh[ni] = *(const s16x8*)&sBh[wv * 32 + ni * 16 + l15][kk * 32 + kh * 8];
                fBl[ni] = *(const s16x8*)&sBl[wv * 32 + ni * 16 + l15][kk * 32 + kh * 8];
            }
            #pragma unroll
            for (int mi = 0; mi < 2; ++mi)
                #pragma unroll
                for (int ni = 0; ni < 2; ++ni) {
                    f32x4 a = acc[mi][ni];
                    a = __builtin_amdgcn_mfma_f32_16x16x32_bf16(fAh[mi], fBh[ni], a, 0, 0, 0);
                    a = __builtin_amdgcn_mfma_f32_16x16x32_bf16(fAl[mi], fBh[ni], a, 0, 0, 0);
                    a = __builtin_amdgcn_mfma_f32_16x16x32_bf16(fAh[mi], fBl[ni], a, 0, 0, 0);
                    acc[mi][ni] = a;
                }
        }
    }

    #pragma unroll
    for (int ni = 0; ni < 2; ++ni) {
        const int col = colB + wv * 32 + ni * 16 + l15;
        const float bval = z ? bias[col] : 0.0f;
        #pragma unroll
        for (int mi = 0; mi < 2; ++mi) {
            #pragma unroll
            for (int r = 0; r < 4; ++r) {
                const int row = rowB + mi * 16 + kh * 4 + r;
                C[(size_t)row * nEd + col] =
                    __builtin_amdgcn_exp2f((acc[mi][ni][r] + bval) * PRESCALE);
            }
        }
    }
}

// ---- kLogSm: pairwise-rcp logits + fused softmax (r16-proven) -----------
__global__ __launch_bounds__(256) void kLogSm(
    const float* __restrict__ X1e,  // [B*S,E] exp2'd
    const float* __restrict__ X2e,  // [B*T,E] exp2'd (bias folded)
    const float* __restrict__ V,    // [E]
    float* __restrict__ attnw)      // [B*T,S] out: softmax weights
{
    const int tg = blockIdx.x, b = blockIdx.y;
    const int tid  = threadIdx.x;
    const int lane = tid & 63;
    const int w    = tid >> 6;
    const int s0 = w * 32;
    const int t0 = tg * 2;

    __shared__ float sm[2][nSq];

    const float4* vp = (const float4*)V;
    float4 n0 = vp[lane * 2], n1 = vp[lane * 2 + 1];
    n0.x *= -2.f; n0.y *= -2.f; n0.z *= -2.f; n0.w *= -2.f;
    n1.x *= -2.f; n1.y *= -2.f; n1.z *= -2.f; n1.w *= -2.f;

    float4 c0[2], c1[2];
    #pragma unroll
    for (int i = 0; i < 2; ++i) {
        const float4* xp = (const float4*)(X2e + ((size_t)b * nTq + t0 + i) * nEd);
        c0[i] = xp[lane * 2];
        c1[i] = xp[lane * 2 + 1];
    }

    const float* X1b = X1e + (size_t)b * nSq * nEd;
    float4 x0 = ((const float4*)(X1b + (size_t)s0 * nEd))[lane * 2];
    float4 x1 = ((const float4*)(X1b + (size_t)s0 * nEd))[lane * 2 + 1];

    #pragma unroll 4
    for (int si = 0; si < 32; ++si) {
        const float4 cx0 = x0, cx1 = x1;
        if (si < 31) {
            const float4* np = (const float4*)(X1b + (size_t)(s0 + si + 1) * nEd);
            x0 = np[lane * 2];
            x1 = np[lane * 2 + 1];
        }
        float a0 = 0.f, a1 = 0.f;
        pair_acc(cx0.x, cx0.y, c0[0].x, c0[0].y, n0.x, n0.y, a0);
        pair_acc(cx0.z, cx0.w, c0[0].z, c0[0].w, n0.z, n0.w, a0);
        pair_acc(cx1.x, cx1.y, c1[0].x, c1[0].y, n1.x, n1.y, a0);
        pair_acc(cx1.z, cx1.w, c1[0].z, c1[0].w, n1.z, n1.w, a0);
        pair_acc(cx0.x, cx0.y, c0[1].x, c0[1].y, n0.x, n0.y, a1);
        pair_acc(cx0.z, cx0.w, c0[1].z, c0[1].w, n0.z, n0.w, a1);
        pair_acc(cx1.x, cx1.y, c1[1].x, c1[1].y, n1.x, n1.y, a1);
        pair_acc(cx1.z, cx1.w, c1[1].z, c1[1].w, n1.z, n1.w, a1);

        const float p0 = a0 + __shfl_xor(a0, 1);
        const float p1 = a1 + __shfl_xor(a1, 1);
        float q = (lane & 1) ? p1 : p0;
        q += __shfl_xor(q, 2);
        q += __shfl_xor(q, 4);
        q += __shfl_xor(q, 8);
        q += __shfl_xor(q, 16);
        q += __shfl_xor(q, 32);
        if (lane < 2) sm[lane][s0 + si] = q;
    }
    __syncthreads();

    if (w < 2) {
        const float l0 = sm[w][lane], l1 = sm[w][lane + 64];
        float m = fmaxf(l0, l1);
        #pragma unroll
        for (int off = 32; off >= 1; off >>= 1)
            m = fmaxf(m, __shfl_xor(m, off));
        const float e0 = __builtin_amdgcn_exp2f((l0 - m) * LOG2E);
        const float e1 = __builtin_amdgcn_exp2f((l1 - m) * LOG2E);
        float sum = e0 + e1;
        #pragma unroll
        for (int off = 32; off >= 1; off >>= 1)
            sum += __shfl_xor(sum, off);
        const float inv = __builtin_amdgcn_rcpf(sum);
        float* ap = attnw + ((size_t)b * nTq + t0 + w) * nSq;
        ap[lane]      = e0 * inv;
        ap[lane + 64] = e1 * inv;
    }
}

// ---- kEncT: standalone fallback (r9-proven) -----------------------------
__global__ __launch_bounds__(256) void kEncT(
    const float* __restrict__ enc, unsigned short* __restrict__ encT)
{
    const int b = blockIdx.z;
    __shared__ float tl[32][33];
    const int r  = threadIdx.x >> 3;
    const int c4 = (threadIdx.x & 7) * 4;
    const int sB = blockIdx.y * 32;
    const int eB = blockIdx.x * 32;
    const float4 v = *(const float4*)&enc[((size_t)b * nSq + sB + r) * nEd + eB + c4];
    tl[r][c4 + 0] = v.x; tl[r][c4 + 1] = v.y;
    tl[r][c4 + 2] = v.z; tl[r][c4 + 3] = v.w;
    __syncthreads();
    unsigned short o[4];
    #pragma unroll
    for (int i = 0; i < 4; ++i) o[i] = to_bf(tl[c4 + i][r]);
    *(ushort4*)&encT[((size_t)b * nEd + eB + r) * nSq + sB + c4] = *(ushort4*)o;
}

// ---- kCtxMM: ctx[b] = bf16(attnw[b]) @ encT[b]^T (r13-proven) -----------
__global__ __launch_bounds__(256) void kCtxMM(
    const float* __restrict__ attnw,          // [B*T,S] f32 weights
    const unsigned short* __restrict__ encT,  // [B*E,S]
    float* __restrict__ ctx)                  // [B*T,E]
{
    const int b  = blockIdx.z;
    const int tB = blockIdx.y * 32;
    const int eB = blockIdx.x * 64;

    __shared__ unsigned short sA[32][136];
    __shared__ unsigned short sB[64][136];

    const int tid  = threadIdx.x;
    const int lane = tid & 63;
    const int w    = tid >> 6;
    const int wm = (w >> 1) * 16;
    const int wn = (w & 1) * 32;
    const int l15 = lane & 15;
    const int kh  = lane >> 4;

    {
        const int r = tid >> 3, c = (tid & 7) * 16;
        const float* ap = &attnw[((size_t)b * nTq + tB + r) * nSq + c];
        unsigned short h[16];
        #pragma unroll
        for (int q = 0; q < 4; ++q) {
            const float4 v = *(const float4*)(ap + 4 * q);
            h[4 * q + 0] = to_bf(v.x); h[4 * q + 1] = to_bf(v.y);
            h[4 * q + 2] = to_bf(v.z); h[4 * q + 3] = to_bf(v.w);
        }
        *(s16x8*)&sA[r][c]     = *(s16x8*)&h[0];
        *(s16x8*)&sA[r][c + 8] = *(s16x8*)&h[8];
    }
    {
        const int r = tid >> 2, c = (tid & 3) * 32;
        const size_t o = ((size_t)b * nEd + eB + r) * nSq + c;
        *(s16x8*)&sB[r][c]      = *(const s16x8*)&encT[o];
        *(s16x8*)&sB[r][c + 8]  = *(const s16x8*)&encT[o + 8];
        *(s16x8*)&sB[r][c + 16] = *(const s16x8*)&encT[o + 16];
        *(s16x8*)&sB[r][c + 24] = *(const s16x8*)&encT[o + 24];
    }
    __syncthreads();

    f32x4 acc[2] = {};
    #pragma unroll
    for (int kk = 0; kk < 4; ++kk) {
        const s16x8 fA = *(const s16x8*)&sA[wm + l15][kk * 32 + kh * 8];
        #pragma unroll
        for (int ni = 0; ni < 2; ++ni) {
            const s16x8 fB = *(const s16x8*)&sB[wn + ni * 16 + l15][kk * 32 + kh * 8];
            acc[ni] = __builtin_amdgcn_mfma_f32_16x16x32_bf16(fA, fB, acc[ni], 0, 0, 0);
        }
    }

    #pragma unroll
    for (int ni = 0; ni < 2; ++ni) {
        const int e = eB + wn + ni * 16 + l15;
        #pragma unroll
        for (int r = 0; r < 4; ++r) {
            const int t = tB + wm + kh * 4 + r;
            ctx[((size_t)b * nTq + t) * nEd + e] = acc[ni][r];
        }
    }
}

extern "C" void kernel_launch(void* const* d_in, const int* in_sizes, int n_in,
                              void* d_out, int out_size, void* d_ws, size_t ws_size,
                              hipStream_t stream) {
    const float* enc = (const float*)d_in[0];   // [16,128,512]
    const float* dec = (const float*)d_in[1];   // [16,128,512]
    const float* W1  = (const float*)d_in[2];   // [512,512]
    const float* W2  = (const float*)d_in[3];   // [512,512]
    const float* bv  = (const float*)d_in[4];   // [512]
    const float* V   = (const float*)d_in[5];   // [512]

    float* ctx   = (float*)d_out;                           // [16,128,512] 4MB
    float* attnw = (float*)d_out + (size_t)nBt * nTq * nEd; // [16,128,128] 1MB

    // WT (4MB hi+lo) in d_out — dead before kCtxMM writes ctx.
    unsigned short* WT = (unsigned short*)d_out;

    const size_t MB = (size_t)1024 * 1024;
    float* ws0 = (float*)d_ws;                    // exp2((enc@W1)*PS), 4MB
    float* ws1 = ws0 + (size_t)nBt * nSq * nEd;   // exp2((dec@W2+b)*PS), 4MB

    const bool early = ws_size >= 18 * MB + 4096;
    unsigned short* encT = early ? (unsigned short*)((char*)d_ws + 8 * MB)
                                 : (unsigned short*)d_ws;

    if (early) {
        unsigned short* Ah = (unsigned short*)((char*)d_ws + 10 * MB);  // 4MB
        unsigned short* Al = (unsigned short*)((char*)d_ws + 14 * MB);  // 4MB
        kPrep<<<dim3(2560), dim3(256), 0, stream>>>(
            W1, W2, WT, enc, dec, encT, Ah, Al);
        kMgemmC<<<dim3(nEd / 128, (nBt * nSq) / 32, 2), dim3(256), 0, stream>>>(
            Ah, Al, WT, bv, ws0, ws1);
        kLogSm<<<dim3(nTq / 2, nBt), dim3(256), 0, stream>>>(ws0, ws1, V, attnw);
    } else {
        kPrep<<<dim3(512), dim3(256), 0, stream>>>(
            W1, W2, WT, enc, dec, encT, nullptr, nullptr);
        kMgemmB<<<dim3(nEd / 128, (nBt * nSq) / 32, 2), dim3(256), 0, stream>>>(
            enc, dec, WT, bv, ws0, ws1);
        kLogSm<<<dim3(nTq / 2, nBt), dim3(256), 0, stream>>>(ws0, ws1, V, attnw);
        kEncT<<<dim3(nEd / 32, nSq / 32, nBt), dim3(256), 0, stream>>>(enc, encT);
    }
    kCtxMM<<<dim3(nEd / 64, nTq / 32, nBt), dim3(256), 0, stream>>>(
        attnw, encT, ctx);
}